// Round 8
// baseline (110.952 us; speedup 1.0000x reference)
//
#include <hip/hip_runtime.h>

// SimpleMatcher: B=128, N=900 preds, T=300 targets.
// out = [pred_idx (B*T), valid (B*T), max_iou (B*T)] as float.
//
// R13: R12 counters (46.4us, VALUBusy 60%, Occ 26%) give 196 SIMD-cyc per
// wave-iteration vs ~60 cyc of pure issue -> the loop is LDS-LATENCY
// bound (ds_read_b128 ~120cyc into a short dependent chain; VGPR=44
// keeps too few reads in flight). More TLP (R11->R12) barely moved it.
// Fix: eliminate in-loop memory entirely. Register-file broadcast:
// each lane loads ITS OWN pred from global once per 64-iter batch
// (coalesced float4, one amortized ~500cyc stall per 64 iters),
// transforms to (x0,y0,x1,y1,pw,ph,pa) in 7 VGPRs; inner loop reads
// pred k via v_readlane (VALU->SGPR, no LDS pipe, tiny fixed latency).
// Each GIoU inst touches <=1 SGPR (legal VALU form). Wave constants pass
// through readfirstlane so the readlane index is analysis-uniform (no
// waterfall). LDS staging deleted; LDS = 6KB reduce only.
// Geometry = R12 (640 blocks x 512 thr, 8 waves, preds 4x113+4x112).
// Numerics bit-identical to R12 (passed, absmax 1.0): same expression
// order, MARGIN 2e-5 + bit-exact winner recompute + exact rescan.
// Fixed floor: harness 256MiB ws-poison fill (~40us) stays in-window.

#define BB 128
#define NN 900
#define TT 300
#define TCHUNKS 5      // ceil(TT/64) target chunks per batch
#define WPB 8          // waves per block
#define MARGIN 2e-5f

__device__ __forceinline__ float rl(float v, int k) {
    return __int_as_float(__builtin_amdgcn_readlane(__float_as_int(v), k));
}

// Bit-exact GIoU in numpy's exact expression order.
__device__ __forceinline__ float giou_exact(float4 pb, float4 tb) {
#pragma clang fp contract(off)
    float px0 = pb.x - 0.5f * pb.z, py0 = pb.y - 0.5f * pb.w;
    float px1 = pb.x + 0.5f * pb.z, py1 = pb.y + 0.5f * pb.w;
    float tx0 = tb.x - 0.5f * tb.z, ty0 = tb.y - 0.5f * tb.w;
    float tx1 = tb.x + 0.5f * tb.z, ty1 = tb.y + 0.5f * tb.w;
    float pa = (px1 - px0) * (py1 - py0);
    float ta = (tx1 - tx0) * (ty1 - ty0);
    float w  = fmaxf(fminf(px1, tx1) - fmaxf(px0, tx0), 0.f);
    float h  = fmaxf(fminf(py1, ty1) - fmaxf(py0, ty0), 0.f);
    float inter = w * h;
    float uni   = pa + ta - inter;
    float iou   = inter / uni;            // correctly-rounded IEEE div
    float ew = fmaxf(fmaxf(px1, tx1) - fminf(px0, tx0), 0.f);
    float eh = fmaxf(fmaxf(py1, ty1) - fminf(py0, ty0), 0.f);
    float ea = ew * eh;
    return iou - (ea - uni) / ea;         // correctly-rounded IEEE div
}

// One GIoU step; pred scalars are wave-uniform (SGPRs via readlane).
// Each VALU inst reads at most one of them. Same FP ops/order as R12.
__device__ __forceinline__ void giou_rl_step(
    const float sx0, const float sy0, const float sx1, const float sy1,
    const float spw, const float sph, const float spa,
    const float tx0, const float ty0, const float tx1, const float ty1,
    const float tw, const float th, const float ta, const int kidx,
    float& best, float& second, int& bidxl)
{
    const float m1x = fminf(sx1, tx1);
    const float M0x = fmaxf(sx0, tx0);
    const float wr  = m1x - M0x;          // unclamped intersect width
    const float w   = fmaxf(wr, 0.f);
    const float m1y = fminf(sy1, ty1);
    const float M0y = fmaxf(sy0, ty0);
    const float hr  = m1y - M0y;
    const float h   = fmaxf(hr, 0.f);
    const float inter = w * h;
    const float uni   = (spa + ta) - inter;
    // min+max=sum identity: ew = max(px1,tx1)-min(px0,tx0) = pw+tw-wr
    const float ew = (spw + tw) - wr;
    const float eh = (sph + th) - hr;
    const float ea = ew * eh;
    // g = inter/uni - (ea-uni)/ea == (inter*ea + uni*(uni-ea))/(uni*ea)
    const float num = fmaf(inter, ea, uni * (uni - ea));
    const float g   = num * __builtin_amdgcn_rcpf(uni * ea);

    second = __builtin_amdgcn_fmed3f(g, best, second);  // new 2nd-max
    if (g > best) bidxl = kidx;
    best = fmaxf(best, g);
}

// Grid: BB * TCHUNKS = 640 blocks, 512 threads (8 waves). Block owns
// (b, 64-target chunk); waves split 900 preds 4x113 + 4x112; lane owns
// one target. Preds stream through the register file via readlane.
__global__ __launch_bounds__(512, 4) void matcher_kernel(
    const float4* __restrict__ pred,      // [B*N] cxcywh
    const float4* __restrict__ tgt,       // [B*T] cxcywh
    const unsigned char* __restrict__ mask,
    float* __restrict__ out)
{
    __shared__ float rbv[512], rsv[512];  // cross-wave top-2 reduce (6 KB)
    __shared__ int   riv[512];
    __shared__ int   sflag[64];
    __shared__ int   scount;

    const int tc  = blockIdx.x % TCHUNKS;
    const int b   = blockIdx.x / TCHUNKS;
    const int tid = threadIdx.x;
    const int tl  = tid & 63;
    const int ng  = tid >> 6;

    if (tid == 0) scount = 0;

    // Lane's target (dummy lanes compute but never store).
    const int  t      = tc * 64 + tl;
    const bool tvalid = (t < TT);
    const float4 tb = tgt[b * TT + (tvalid ? t : 0)];
    const float tx0 = tb.x - 0.5f * tb.z;
    const float ty0 = tb.y - 0.5f * tb.w;
    const float tx1 = tb.x + 0.5f * tb.z;
    const float ty1 = tb.y + 0.5f * tb.w;
    const float tw  = tx1 - tx0;
    const float th  = ty1 - ty0;
    const float ta  = tw * th;            // == reference area_t

    // Wave slice: waves 0..3 get 113 preds (64+49), waves 4..7 get 112
    // (64+48). readfirstlane makes these analysis-uniform so the
    // readlane index below is provably uniform (no waterfall).
    const int k0u = __builtin_amdgcn_readfirstlane(
        ng * 112 + (ng < 4 ? ng : 4));
    const int n2u = __builtin_amdgcn_readfirstlane(ng < 4 ? 49 : 48);

    // Batch loads: lane tl holds pred k0u+tl (A) and k0u+64+tl (B).
    // A is always in-range (max 788+63=851). B clamped for unused lanes
    // (used lanes 0..n2u-1 are always in-range; tail wave ends at 899).
    const float4 pA = pred[b * NN + k0u + tl];
    const int idxB  = k0u + 64 + tl;
    const float4 pB = pred[b * NN + (idxB < NN ? idxB : NN - 1)];

    // Transform A (same FP ops as the old staging transform).
    const float qax0 = pA.x - 0.5f * pA.z;
    const float qay0 = pA.y - 0.5f * pA.w;
    const float qax1 = pA.x + 0.5f * pA.z;
    const float qay1 = pA.y + 0.5f * pA.w;
    const float qapw = qax1 - qax0;
    const float qaph = qay1 - qay0;
    const float qapa = qapw * qaph;

    float best = -INFINITY, second = -INFINITY;
    int   bidxl = 0;
    #pragma unroll 8
    for (int k = 0; k < 64; ++k) {        // batch A: preds k0u..k0u+63
        giou_rl_step(rl(qax0, k), rl(qay0, k), rl(qax1, k), rl(qay1, k),
                     rl(qapw, k), rl(qaph, k), rl(qapa, k),
                     tx0, ty0, tx1, ty1, tw, th, ta, k,
                     best, second, bidxl);
    }

    // Transform B.
    const float qbx0 = pB.x - 0.5f * pB.z;
    const float qby0 = pB.y - 0.5f * pB.w;
    const float qbx1 = pB.x + 0.5f * pB.z;
    const float qby1 = pB.y + 0.5f * pB.w;
    const float qbpw = qbx1 - qbx0;
    const float qbph = qby1 - qby0;
    const float qbpa = qbpw * qbph;

    #pragma unroll 8
    for (int k = 0; k < n2u; ++k) {       // batch B: preds k0u+64..
        giou_rl_step(rl(qbx0, k), rl(qby0, k), rl(qbx1, k), rl(qby1, k),
                     rl(qbpw, k), rl(qbph, k), rl(qbpa, k),
                     tx0, ty0, tx1, ty1, tw, th, ta, 64 + k,
                     best, second, bidxl);
    }
    int bidx = k0u + bidxl;               // global pred index

    rbv[tid] = best; rsv[tid] = second; riv[tid] = bidx;
    __syncthreads();

    if (ng == 0) {
        // Combine the 8 wave slices (ascending wave = ascending n).
        for (int s = 1; s < WPB; ++s) {
            const float ob = rbv[s * 64 + tl];
            const float os = rsv[s * 64 + tl];
            const int   oi = riv[s * 64 + tl];
            second = fmaxf(fminf(best, ob), fmaxf(second, os));
            if (ob > best) { best = ob; bidx = oi; }
        }

        if (tvalid) {
            const int bt = b * TT + t;
            if (best - second > MARGIN) {
                // approx argmax provably exact; recompute winner exactly
                const float4 pb = pred[b * NN + bidx];
                const float4 tbr = tgt[bt];
                const float g = giou_exact(pb, tbr);
                const bool valid = (mask[bt] != 0) && (g >= 0.5f);
                out[bt]               = (float)bidx;
                out[BB * TT + bt]     = valid ? 1.f : 0.f;
                out[2 * BB * TT + bt] = g;
            } else {
                const int pos = atomicAdd(&scount, 1);
                sflag[pos] = tl;
            }
        }
    }
    __syncthreads();

    // Cooperative exact rescan of ambiguous targets: one wave per entry.
    const int cnt = scount;
    for (int f = ng; f < cnt; f += WPB) {
        const int fbt = b * TT + tc * 64 + sflag[f];
        const float4 tbr = tgt[fbt];

        float bestx = -INFINITY;
        int   bix   = NN;
        for (int n = tl; n < NN; n += 64) {   // ascending n per lane
            const float4 pb = pred[b * NN + n];
            const float g = giou_exact(pb, tbr);
            if (g > bestx) { bestx = g; bix = n; }
        }
        // cross-lane reduce: max g, lowest n on bit-ties (numpy first-occ.)
        for (int off = 32; off >= 1; off >>= 1) {
            const float ob = __shfl_xor(bestx, off);
            const int   oi = __shfl_xor(bix, off);
            if (ob > bestx || (ob == bestx && oi < bix)) { bestx = ob; bix = oi; }
        }
        if (tl == 0) {
            const bool valid = (mask[fbt] != 0) && (bestx >= 0.5f);
            out[fbt]               = (float)bix;
            out[BB * TT + fbt]     = valid ? 1.f : 0.f;
            out[2 * BB * TT + fbt] = bestx;
        }
    }
}

extern "C" void kernel_launch(void* const* d_in, const int* in_sizes, int n_in,
                              void* d_out, int out_size, void* d_ws, size_t ws_size,
                              hipStream_t stream) {
    const float* pred = (const float*)d_in[0];
    const float* tgt  = (const float*)d_in[1];
    const unsigned char* mask = (const unsigned char*)d_in[2];
    float* out = (float*)d_out;

    matcher_kernel<<<dim3(BB * TCHUNKS), dim3(512), 0, stream>>>(
        (const float4*)pred, (const float4*)tgt, mask, out);
}